// Round 13
// baseline (677.503 us; speedup 1.0000x reference)
//
#include <hip/hip_runtime.h>
#include <hip/hip_fp16.h>
#include <math.h>

#define LEAKY 0.2f
#define BSZ 64

typedef _Float16 f16x8 __attribute__((ext_vector_type(8)));
typedef _Float16 f16x2 __attribute__((ext_vector_type(2)));
typedef float f32x4 __attribute__((ext_vector_type(4)));

union H2 { __half2 h; f16x2 f; int i; };
union H8 { __half2 h[4]; float4 f; };
union H4 { __half2 h[2]; float2 f; };

__device__ inline __half2 shfl_xor_h2(__half2 v, int m) {
    H2 u; u.h = v;
    u.i = __shfl_xor(u.i, m);
    return u.h;
}

// ---------------- kinit: per-node degree count (blocks 0..255)
// ---------------- + W1 transpose + W2 fp16 pair-pack (256..383) ----------------
__global__ __launch_bounds__(256) void kinit(const int* __restrict__ dst,
                                             int* __restrict__ ncnt,
                                             int E, int chunk,
                                             const float* __restrict__ W1,
                                             __half* __restrict__ W1t,
                                             const float* __restrict__ W2,
                                             __half2* __restrict__ W2h2) {
    if (blockIdx.x < 256) {
        int t = threadIdx.x;
        int base = blockIdx.x * chunk;
        int end = min(base + chunk, E);
        for (int e = base + t; e < end; e += 256)
            atomicAdd(&ncnt[dst[e]], 1);        // 400 KB table, L2-resident RMW
    } else {
        int idx = (blockIdx.x - 256) * 256 + threadIdx.x;
        if (idx < 32768) {
            int n = idx >> 8, k = idx & 255;              // W1t[128][256]
            W1t[idx] = __float2half(W1[k * 128 + n]);
        }
        if (idx < 1024) {
            // W2h2[fp*256 + e2*64 + qq*4 + jj] =
            //   ( W2[(qq*8+2fp)*16 + e2*4+jj], W2[(qq*8+2fp+1)*16 + e2*4+jj] )
            int fp = idx >> 8;
            int r  = idx & 255;
            int e2 = r >> 6;
            int qq = (r >> 2) & 15;
            int jj = r & 3;
            float lo = W2[(qq * 8 + 2 * fp)     * 16 + e2 * 4 + jj];
            float hi = W2[(qq * 8 + 2 * fp + 1) * 16 + e2 * 4 + jj];
            W2h2[idx] = __floats2half2_rn(lo, hi);
        }
    }
}

// per-bucket edge sums from ncnt (1563 blocks x 1 wave)
__global__ __launch_bounds__(64) void bsum(const int* __restrict__ ncnt,
                                           int* __restrict__ bhist, int N) {
    int node = blockIdx.x * 64 + threadIdx.x;
    int c = (node < N) ? ncnt[node] : 0;
    #pragma unroll
    for (int off = 32; off; off >>= 1) c += __shfl_down(c, off);
    if (threadIdx.x == 0) bhist[blockIdx.x] = c;
}

// single-block exclusive scan of bucket counts -> bbase
__global__ __launch_bounds__(1024) void bscan(const int* __restrict__ bhist,
                                              int* __restrict__ bbase, int nbuk) {
    __shared__ int s[1024];
    int t = threadIdx.x;
    int v[4]; int sum = 0;
    #pragma unroll
    for (int i = 0; i < 4; ++i) {
        int idx = t * 4 + i;
        v[i] = (idx < nbuk) ? bhist[idx] : 0;
        sum += v[i];
    }
    s[t] = sum; __syncthreads();
    for (int off = 1; off < 1024; off <<= 1) {
        int a = (t >= off) ? s[t - off] : 0;
        __syncthreads();
        s[t] += a;
        __syncthreads();
    }
    int run = (t > 0) ? s[t - 1] : 0;
    #pragma unroll
    for (int i = 0; i < 4; ++i) {
        int idx = t * 4 + i;
        if (idx < nbuk) { bbase[idx] = run; run += v[i]; }
    }
    if (t == 1023) bbase[nbuk] = s[1023];
}

// rowptr + dis + self-loop + per-node cursor from ncnt (1563 blocks x 1 wave)
__global__ __launch_bounds__(64) void kplace2(const int* __restrict__ ncnt,
                                              const int* __restrict__ bbase,
                                              int* __restrict__ rowptr,
                                              float* __restrict__ dis,
                                              int* __restrict__ col,
                                              int* __restrict__ gcur, int N) {
    int b = blockIdx.x, t = threadIdx.x;
    int node = b * 64 + t;
    int c = (node < N) ? ncnt[node] + 1 : 0;     // +1 self-loop
    int incl = c;
    #pragma unroll
    for (int off = 1; off < 64; off <<= 1) {
        int v = __shfl_up(incl, off);
        if (t >= off) incl += v;
    }
    int colbase = bbase[b] + b * 64;             // 64 self-loops per full bucket
    if (node < N) {
        int r = colbase + incl - c;
        rowptr[node] = r;
        dis[node] = rsqrtf((float)c);
        col[r] = node;                           // self-loop first
        gcur[node] = r + 1;
        if (node == N - 1) rowptr[N] = colbase + incl;
    }
}

// direct scatter: col[atomicAdd(gcur[dst])] = src  (no ebuf)
__global__ __launch_bounds__(256) void kscatter_direct(
        const int* __restrict__ src, const int* __restrict__ dst,
        int* __restrict__ gcur, int* __restrict__ col, int E, int chunk) {
    int t = threadIdx.x;
    int base = blockIdx.x * chunk;
    int end = min(base + chunk, E);
    for (int e = base + t; e < end; e += 256) {
        int d = dst[e];
        int p = atomicAdd(&gcur[d], 1);
        col[p] = src[e];
    }
}

// ---------------- GEMM1: [M,256]fp32 @ W1t[128,256]fp16 -> fp16, *= dis[row] ----------------
__global__ __launch_bounds__(256) void gemm1_mfma(
        const float* __restrict__ x, const __half* __restrict__ W1t,
        const float* __restrict__ dis, __half* __restrict__ C, int M) {
    int wave = threadIdx.x >> 6;
    int lane = threadIdx.x & 63;
    int m = lane & 15, q = lane >> 4;
    int row0 = (blockIdx.x * 4 + wave) * 16;
    int arow = row0 + m;
    bool aval = arow < M;
    const float* xr = x + (size_t)arow * 256 + q * 8;
    f32x4 acc[8];
    #pragma unroll
    for (int c = 0; c < 8; ++c) acc[c] = (f32x4){0.f, 0.f, 0.f, 0.f};
    for (int k0 = 0; k0 < 256; k0 += 32) {
        f16x8 a;
        if (aval) {
            float4 v0 = *(const float4*)(xr + k0);
            float4 v1 = *(const float4*)(xr + k0 + 4);
            a[0] = (_Float16)v0.x; a[1] = (_Float16)v0.y;
            a[2] = (_Float16)v0.z; a[3] = (_Float16)v0.w;
            a[4] = (_Float16)v1.x; a[5] = (_Float16)v1.y;
            a[6] = (_Float16)v1.z; a[7] = (_Float16)v1.w;
        } else {
            #pragma unroll
            for (int i = 0; i < 8; ++i) a[i] = (_Float16)0.f;
        }
        #pragma unroll
        for (int c = 0; c < 8; ++c) {
            f16x8 b = *(const f16x8*)(W1t + (size_t)(c * 16 + m) * 256 + k0 + q * 8);
            acc[c] = __builtin_amdgcn_mfma_f32_16x16x32_f16(a, b, acc[c], 0, 0, 0);
        }
    }
    float dw[4];
    #pragma unroll
    for (int r = 0; r < 4; ++r) {
        int rr = row0 + q * 4 + r;
        dw[r] = (rr < M) ? dis[rr] : 0.f;
    }
    #pragma unroll
    for (int c = 0; c < 8; ++c) {
        #pragma unroll
        for (int r = 0; r < 4; ++r) {
            int rr = row0 + q * 4 + r;
            if (rr < M)
                C[(size_t)rr * 128 + c * 16 + m] = __float2half(acc[c][r] * dw[r]);
        }
    }
}

// ---------------- prop128g2: aggregate h1 (128 fp16) + fused layer-2 GEMM epilogue ----------------
// out = h2h[n][16] = dis[n] * ( leaky(dis[n]*sum + b1) @ W2 )
// W2 staged in LDS as fp16 feature-PAIRS (4 KB, pre-packed by kinit, linear staging);
// product via v_dot2_f32_f16.
__global__ __launch_bounds__(256) void prop128g2(
        const __half* __restrict__ h, const int* __restrict__ rowptr,
        const int* __restrict__ col, const float* __restrict__ dis,
        const float* __restrict__ bias, const __half2* __restrict__ W2h2,
        __half* __restrict__ out, int N) {
    __shared__ __half2 swh[1024];           // 4 KB
    {
        int k = threadIdx.x;                // 256 threads x 16 B = 4 KB
        ((float4*)swh)[k] = ((const float4*)W2h2)[k];
    }
    __syncthreads();

    int n = (blockIdx.x * 256 + threadIdx.x) >> 6;
    if (n >= N) return;
    int lane = threadIdx.x & 63;
    int eo = lane >> 4;
    int q = lane & 15;
    const float4* __restrict__ h4 = (const float4*)h;
    int beg = rowptr[n], end = rowptr[n + 1];
    __half2 acc[4];
    acc[0] = acc[1] = acc[2] = acc[3] = __float2half2_rn(0.f);
    int j = beg + eo;
    for (; j + 28 < end; j += 32) {     // 32 edges in flight per wave
        int s0 = col[j],      s1 = col[j + 4],  s2 = col[j + 8],  s3 = col[j + 12];
        int s4 = col[j + 16], s5 = col[j + 20], s6 = col[j + 24], s7 = col[j + 28];
        H8 u0, u1, u2, u3, u4, u5, u6, u7;
        u0.f = h4[(size_t)s0 * 16 + q];
        u1.f = h4[(size_t)s1 * 16 + q];
        u2.f = h4[(size_t)s2 * 16 + q];
        u3.f = h4[(size_t)s3 * 16 + q];
        u4.f = h4[(size_t)s4 * 16 + q];
        u5.f = h4[(size_t)s5 * 16 + q];
        u6.f = h4[(size_t)s6 * 16 + q];
        u7.f = h4[(size_t)s7 * 16 + q];
        #pragma unroll
        for (int i = 0; i < 4; ++i) acc[i] = __hadd2(acc[i], u0.h[i]);
        #pragma unroll
        for (int i = 0; i < 4; ++i) acc[i] = __hadd2(acc[i], u1.h[i]);
        #pragma unroll
        for (int i = 0; i < 4; ++i) acc[i] = __hadd2(acc[i], u2.h[i]);
        #pragma unroll
        for (int i = 0; i < 4; ++i) acc[i] = __hadd2(acc[i], u3.h[i]);
        #pragma unroll
        for (int i = 0; i < 4; ++i) acc[i] = __hadd2(acc[i], u4.h[i]);
        #pragma unroll
        for (int i = 0; i < 4; ++i) acc[i] = __hadd2(acc[i], u5.h[i]);
        #pragma unroll
        for (int i = 0; i < 4; ++i) acc[i] = __hadd2(acc[i], u6.h[i]);
        #pragma unroll
        for (int i = 0; i < 4; ++i) acc[i] = __hadd2(acc[i], u7.h[i]);
    }
    for (; j + 12 < end; j += 16) {
        int s0 = col[j], s1 = col[j + 4], s2 = col[j + 8], s3 = col[j + 12];
        H8 u0, u1, u2, u3;
        u0.f = h4[(size_t)s0 * 16 + q];
        u1.f = h4[(size_t)s1 * 16 + q];
        u2.f = h4[(size_t)s2 * 16 + q];
        u3.f = h4[(size_t)s3 * 16 + q];
        #pragma unroll
        for (int i = 0; i < 4; ++i) acc[i] = __hadd2(acc[i], u0.h[i]);
        #pragma unroll
        for (int i = 0; i < 4; ++i) acc[i] = __hadd2(acc[i], u1.h[i]);
        #pragma unroll
        for (int i = 0; i < 4; ++i) acc[i] = __hadd2(acc[i], u2.h[i]);
        #pragma unroll
        for (int i = 0; i < 4; ++i) acc[i] = __hadd2(acc[i], u3.h[i]);
    }
    for (; j + 4 < end; j += 8) {
        int s0 = col[j], s1 = col[j + 4];
        H8 u0, u1;
        u0.f = h4[(size_t)s0 * 16 + q];
        u1.f = h4[(size_t)s1 * 16 + q];
        #pragma unroll
        for (int i = 0; i < 4; ++i) acc[i] = __hadd2(acc[i], u0.h[i]);
        #pragma unroll
        for (int i = 0; i < 4; ++i) acc[i] = __hadd2(acc[i], u1.h[i]);
    }
    for (; j < end; j += 4) {
        int s = col[j];
        H8 u; u.f = h4[(size_t)s * 16 + q];
        #pragma unroll
        for (int i = 0; i < 4; ++i) acc[i] = __hadd2(acc[i], u.h[i]);
    }
    #pragma unroll
    for (int i = 0; i < 4; ++i) {
        acc[i] = __hadd2(acc[i], shfl_xor_h2(acc[i], 16));
        acc[i] = __hadd2(acc[i], shfl_xor_h2(acc[i], 32));
    }
    // --- fused epilogue ---
    float dn = dis[n];
    const float4* b4 = (const float4*)bias;
    float4 bA = b4[q * 2];
    float4 bB = b4[q * 2 + 1];
    float2 f0 = __half22float2(acc[0]);
    float2 f1 = __half22float2(acc[1]);
    float2 f2 = __half22float2(acc[2]);
    float2 f3 = __half22float2(acc[3]);
    float xf[8];
    xf[0] = fmaf(dn, f0.x, bA.x); xf[1] = fmaf(dn, f0.y, bA.y);
    xf[2] = fmaf(dn, f1.x, bA.z); xf[3] = fmaf(dn, f1.y, bA.w);
    xf[4] = fmaf(dn, f2.x, bB.x); xf[5] = fmaf(dn, f2.y, bB.y);
    xf[6] = fmaf(dn, f3.x, bB.z); xf[7] = fmaf(dn, f3.y, bB.w);
    #pragma unroll
    for (int i = 0; i < 8; ++i) xf[i] = xf[i] > 0.f ? xf[i] : LEAKY * xf[i];
    H2 xh[4];
    #pragma unroll
    for (int fp = 0; fp < 4; ++fp)
        xh[fp].h = __floats2half2_rn(xf[2 * fp], xf[2 * fp + 1]);
    float p0 = 0.f, p1 = 0.f, p2 = 0.f, p3 = 0.f;
    #pragma unroll
    for (int fp = 0; fp < 4; ++fp) {
        H8 wv;
        wv.f = *(const float4*)&swh[fp * 256 + eo * 64 + q * 4];
        H2 w0, w1, w2, w3;
        w0.h = wv.h[0]; w1.h = wv.h[1]; w2.h = wv.h[2]; w3.h = wv.h[3];
        p0 = __builtin_amdgcn_fdot2(xh[fp].f, w0.f, p0, false);
        p1 = __builtin_amdgcn_fdot2(xh[fp].f, w1.f, p1, false);
        p2 = __builtin_amdgcn_fdot2(xh[fp].f, w2.f, p2, false);
        p3 = __builtin_amdgcn_fdot2(xh[fp].f, w3.f, p3, false);
    }
    #pragma unroll
    for (int mm = 1; mm < 16; mm <<= 1) {   // reduce over 16 q-lanes
        p0 += __shfl_xor(p0, mm);
        p1 += __shfl_xor(p1, mm);
        p2 += __shfl_xor(p2, mm);
        p3 += __shfl_xor(p3, mm);
    }
    if (q == 0) {
        H4 w;
        w.h[0] = __floats2half2_rn(p0 * dn, p1 * dn);
        w.h[1] = __floats2half2_rn(p2 * dn, p3 * dn);
        ((float2*)out)[(size_t)n * 4 + eo] = w.f;
    }
}

// ---------------- prop16: 8 lanes/node, float4 gathers (2 lanes/row) ----------------
__global__ __launch_bounds__(256) void prop16(
        const __half* __restrict__ h, const int* __restrict__ rowptr,
        const int* __restrict__ col, const float* __restrict__ dis,
        const float* __restrict__ bias, __half* __restrict__ outp, int N) {
    int t = blockIdx.x * 256 + threadIdx.x;
    int n = t >> 3;
    if (n >= N) return;
    int li = threadIdx.x & 7;
    int slot = li >> 1;                  // 0..3 edge slot
    int half = li & 1;                   // 0..1 half-row (16 B)
    const float4* __restrict__ h4 = (const float4*)h;
    int beg = rowptr[n], end = rowptr[n + 1];
    __half2 acc[4];
    acc[0] = acc[1] = acc[2] = acc[3] = __float2half2_rn(0.f);
    int j = beg + slot;
    for (; j + 12 < end; j += 16) {
        int s0 = col[j], s1 = col[j + 4], s2 = col[j + 8], s3 = col[j + 12];
        H8 u0, u1, u2, u3;
        u0.f = h4[(size_t)s0 * 2 + half];
        u1.f = h4[(size_t)s1 * 2 + half];
        u2.f = h4[(size_t)s2 * 2 + half];
        u3.f = h4[(size_t)s3 * 2 + half];
        #pragma unroll
        for (int i = 0; i < 4; ++i) acc[i] = __hadd2(acc[i], u0.h[i]);
        #pragma unroll
        for (int i = 0; i < 4; ++i) acc[i] = __hadd2(acc[i], u1.h[i]);
        #pragma unroll
        for (int i = 0; i < 4; ++i) acc[i] = __hadd2(acc[i], u2.h[i]);
        #pragma unroll
        for (int i = 0; i < 4; ++i) acc[i] = __hadd2(acc[i], u3.h[i]);
    }
    for (; j + 4 < end; j += 8) {
        int s0 = col[j], s1 = col[j + 4];
        H8 u0, u1;
        u0.f = h4[(size_t)s0 * 2 + half];
        u1.f = h4[(size_t)s1 * 2 + half];
        #pragma unroll
        for (int i = 0; i < 4; ++i) acc[i] = __hadd2(acc[i], u0.h[i]);
        #pragma unroll
        for (int i = 0; i < 4; ++i) acc[i] = __hadd2(acc[i], u1.h[i]);
    }
    for (; j < end; j += 4) {
        int s = col[j];
        H8 u; u.f = h4[(size_t)s * 2 + half];
        #pragma unroll
        for (int i = 0; i < 4; ++i) acc[i] = __hadd2(acc[i], u.h[i]);
    }
    #pragma unroll
    for (int i = 0; i < 4; ++i) {
        acc[i] = __hadd2(acc[i], shfl_xor_h2(acc[i], 2));
        acc[i] = __hadd2(acc[i], shfl_xor_h2(acc[i], 4));
    }
    if (slot == 0) {                     // lanes li in {0,1}: full sums for their half
        float dn = dis[n];
        const float4* b4 = (const float4*)bias;
        float4 bA = b4[half * 2];
        float4 bB = b4[half * 2 + 1];
        float2 f0 = __half22float2(acc[0]);
        float2 f1 = __half22float2(acc[1]);
        float2 f2 = __half22float2(acc[2]);
        float2 f3 = __half22float2(acc[3]);
        float o0 = fmaf(dn, f0.x, bA.x), o1 = fmaf(dn, f0.y, bA.y);
        float o2 = fmaf(dn, f1.x, bA.z), o3 = fmaf(dn, f1.y, bA.w);
        float o4 = fmaf(dn, f2.x, bB.x), o5 = fmaf(dn, f2.y, bB.y);
        float o6 = fmaf(dn, f3.x, bB.z), o7 = fmaf(dn, f3.y, bB.w);
        o0 = o0 > 0.f ? o0 : LEAKY * o0;  o1 = o1 > 0.f ? o1 : LEAKY * o1;
        o2 = o2 > 0.f ? o2 : LEAKY * o2;  o3 = o3 > 0.f ? o3 : LEAKY * o3;
        o4 = o4 > 0.f ? o4 : LEAKY * o4;  o5 = o5 > 0.f ? o5 : LEAKY * o5;
        o6 = o6 > 0.f ? o6 : LEAKY * o6;  o7 = o7 > 0.f ? o7 : LEAKY * o7;
        o0 *= dn; o1 *= dn; o2 *= dn; o3 *= dn;
        o4 *= dn; o5 *= dn; o6 *= dn; o7 *= dn;
        H8 w;
        w.h[0] = __floats2half2_rn(o0, o1);
        w.h[1] = __floats2half2_rn(o2, o3);
        w.h[2] = __floats2half2_rn(o4, o5);
        w.h[3] = __floats2half2_rn(o6, o7);
        ((float4*)outp)[(size_t)n * 2 + half] = w.f;
    }
}

// ---------------- prop16_gemm3: 8 lanes/node float4 gather -> p3 -> @W3 + b3 -> out ----------------
__global__ __launch_bounds__(256) void prop16_gemm3(
        const __half* __restrict__ h, const int* __restrict__ rowptr,
        const int* __restrict__ col, const float* __restrict__ dis,
        const float* __restrict__ W3, const float* __restrict__ b3,
        float* __restrict__ out, int N) {
    __shared__ float sw[640];
    __shared__ float sb[40];
    int t0 = threadIdx.x;
    for (int i = t0; i < 640; i += 256) sw[i] = W3[i];
    if (t0 < 40) sb[t0] = b3[t0];
    __syncthreads();
    int t = blockIdx.x * 256 + t0;
    int n = t >> 3;
    if (n >= N) return;
    int li = t0 & 7;
    int slot = li >> 1;
    int half = li & 1;
    const float4* __restrict__ h4 = (const float4*)h;
    int beg = rowptr[n], end = rowptr[n + 1];
    __half2 acc[4];
    acc[0] = acc[1] = acc[2] = acc[3] = __float2half2_rn(0.f);
    int j = beg + slot;
    for (; j + 12 < end; j += 16) {
        int s0 = col[j], s1 = col[j + 4], s2 = col[j + 8], s3 = col[j + 12];
        H8 u0, u1, u2, u3;
        u0.f = h4[(size_t)s0 * 2 + half];
        u1.f = h4[(size_t)s1 * 2 + half];
        u2.f = h4[(size_t)s2 * 2 + half];
        u3.f = h4[(size_t)s3 * 2 + half];
        #pragma unroll
        for (int i = 0; i < 4; ++i) acc[i] = __hadd2(acc[i], u0.h[i]);
        #pragma unroll
        for (int i = 0; i < 4; ++i) acc[i] = __hadd2(acc[i], u1.h[i]);
        #pragma unroll
        for (int i = 0; i < 4; ++i) acc[i] = __hadd2(acc[i], u2.h[i]);
        #pragma unroll
        for (int i = 0; i < 4; ++i) acc[i] = __hadd2(acc[i], u3.h[i]);
    }
    for (; j + 4 < end; j += 8) {
        int s0 = col[j], s1 = col[j + 4];
        H8 u0, u1;
        u0.f = h4[(size_t)s0 * 2 + half];
        u1.f = h4[(size_t)s1 * 2 + half];
        #pragma unroll
        for (int i = 0; i < 4; ++i) acc[i] = __hadd2(acc[i], u0.h[i]);
        #pragma unroll
        for (int i = 0; i < 4; ++i) acc[i] = __hadd2(acc[i], u1.h[i]);
    }
    for (; j < end; j += 4) {
        int s = col[j];
        H8 u; u.f = h4[(size_t)s * 2 + half];
        #pragma unroll
        for (int i = 0; i < 4; ++i) acc[i] = __hadd2(acc[i], u.h[i]);
    }
    #pragma unroll
    for (int i = 0; i < 4; ++i) {
        acc[i] = __hadd2(acc[i], shfl_xor_h2(acc[i], 2));
        acc[i] = __hadd2(acc[i], shfl_xor_h2(acc[i], 4));
    }
    // exchange halves: every lane assembles the full 16-feature row
    __half2 oth[4];
    #pragma unroll
    for (int i = 0; i < 4; ++i) oth[i] = shfl_xor_h2(acc[i], 1);
    float dn = dis[n];
    float p[16];
    #pragma unroll
    for (int i = 0; i < 4; ++i) {
        __half2 lo = half ? oth[i] : acc[i];     // features 0..7
        __half2 hi = half ? acc[i] : oth[i];     // features 8..15
        float2 a = __half22float2(lo);
        float2 b = __half22float2(hi);
        p[2 * i]     = dn * a.x;  p[2 * i + 1]     = dn * a.y;
        p[8 + 2 * i] = dn * b.x;  p[8 + 2 * i + 1] = dn * b.y;
    }
    float o0 = 0.f, o1 = 0.f, o2 = 0.f, o3 = 0.f, o4 = 0.f;
    #pragma unroll
    for (int k = 0; k < 16; ++k) {
        const float* wr = &sw[k * 40 + li];
        o0 = fmaf(p[k], wr[0],  o0);
        o1 = fmaf(p[k], wr[8],  o1);
        o2 = fmaf(p[k], wr[16], o2);
        o3 = fmaf(p[k], wr[24], o3);
        o4 = fmaf(p[k], wr[32], o4);
    }
    float* orow = out + (size_t)n * 40;
    orow[li]      = o0 + sb[li];
    orow[li + 8]  = o1 + sb[li + 8];
    orow[li + 16] = o2 + sb[li + 16];
    orow[li + 24] = o3 + sb[li + 24];
    orow[li + 32] = o4 + sb[li + 32];
}

// ---------------- launch ----------------

extern "C" void kernel_launch(void* const* d_in, const int* in_sizes, int n_in,
                              void* d_out, int out_size, void* d_ws, size_t ws_size,
                              hipStream_t stream) {
    const float* x  = (const float*)d_in[0];
    const int*   ei = (const int*)d_in[1];
    const float* W1 = (const float*)d_in[2];
    const float* b1 = (const float*)d_in[3];
    const float* W2 = (const float*)d_in[4];
    const float* b2 = (const float*)d_in[5];
    const float* W3 = (const float*)d_in[6];
    const float* b3 = (const float*)d_in[7];
    float* out = (float*)d_out;

    int N = in_sizes[0] / 256;   // 100000
    int E = in_sizes[1] / 2;     // 3200000
    const int* src = ei;
    const int* dst = ei + E;
    int NBUK = (N + BSZ - 1) / BSZ;   // 1563

    char* w = (char*)d_ws;
    auto alloc = [&](size_t bytes) {
        char* p = w;
        w += (bytes + 255) & ~(size_t)255;
        return p;
    };
    int*     rowptr  = (int*)    alloc((size_t)(N + 1) * 4);
    int*     bhist   = (int*)    alloc((size_t)NBUK * 4);
    int*     bbase   = (int*)    alloc((size_t)(NBUK + 1) * 4);
    int*     ncnt    = (int*)    alloc((size_t)N * 4);
    int*     gcur    = (int*)    alloc((size_t)N * 4);
    int*     colx    = (int*)    alloc((size_t)(E + N) * 4);
    float*   dis     = (float*)  alloc((size_t)N * 4);
    __half*  W1t     = (__half*) alloc((size_t)128 * 256 * 2);
    __half2* W2h2    = (__half2*)alloc((size_t)1024 * 4);
    __half*  h1h     = (__half*) alloc((size_t)N * 128 * 2);
    __half*  h2h     = (__half*) alloc((size_t)N * 16 * 2);
    __half*  x2h     = (__half*) alloc((size_t)N * 16 * 2);

    int SC_BLOCKS = 256;
    int chunk = (E + SC_BLOCKS - 1) / SC_BLOCKS;

    (void)hipMemsetAsync(ncnt, 0, (size_t)N * 4, stream);
    kinit   <<<384, 256, 0, stream>>>(dst, ncnt, E, chunk, W1, W1t, W2, W2h2);
    bsum    <<<NBUK, 64, 0, stream>>>(ncnt, bhist, N);
    bscan   <<<1, 1024, 0, stream>>>(bhist, bbase, NBUK);
    kplace2 <<<NBUK, 64, 0, stream>>>(ncnt, bbase, rowptr, dis, colx, gcur, N);
    kscatter_direct<<<SC_BLOCKS, 256, 0, stream>>>(src, dst, gcur, colx, E, chunk);

    int gtiles = (N + 63) / 64;
    gemm1_mfma<<<gtiles, 256, 0, stream>>>(x, W1t, dis, h1h, N);
    prop128g2 <<<(N * 64 + 255) / 256, 256, 0, stream>>>(h1h, rowptr, colx,
                                                         dis, b1, W2h2, h2h, N);
    prop16    <<<(N * 8 + 255) / 256, 256, 0, stream>>>(h2h, rowptr, colx,
                                                        dis, b2, x2h, N);
    prop16_gemm3<<<(N * 8 + 255) / 256, 256, 0, stream>>>(x2h, rowptr, colx,
                                                          dis, W3, b3, out, N);
}